// Round 16
// baseline (1143.373 us; speedup 1.0000x reference)
//
#include <hip/hip_runtime.h>

#define N_NODES 100000
#define N_EDGES 500000
#define NODE_IN 60
#define EDGE_IN 8
#define HID 256
#define NLAYERS 8
#define NGRAPH 64
#define BN_EPS 1e-5f
#define SY_PITCH 520   // 512 + 8: breaks the all-rows-bank-0 alignment, keeps 8B align

typedef __attribute__((ext_vector_type(4))) float f32x4;
typedef __attribute__((ext_vector_type(4))) short short4v;
typedef __attribute__((ext_vector_type(8))) short short8v;
typedef __attribute__((ext_vector_type(4))) unsigned short u16x4;
typedef unsigned short u16;

__device__ __forceinline__ u16 f2bf(float f) {
    unsigned int u = __builtin_bit_cast(unsigned int, f);
    u += 0x7fffu + ((u >> 16) & 1u);
    return (u16)(u >> 16);
}
__device__ __forceinline__ float bf2f(u16 u) {
    unsigned int x = ((unsigned int)u) << 16;
    return __builtin_bit_cast(float, x);
}
__device__ __forceinline__ float lo_f(unsigned int d) {
    return __builtin_bit_cast(float, d << 16);
}
__device__ __forceinline__ float hi_f(unsigned int d) {
    return __builtin_bit_cast(float, d & 0xffff0000u);
}

// async global->LDS, 16B per lane; lds dest = wave-uniform base + lane*16
__device__ __forceinline__ void g2lds16(const void* g, void* l) {
    __builtin_amdgcn_global_load_lds(
        (const __attribute__((address_space(1))) void*)g,
        (__attribute__((address_space(3))) void*)l, 16, 0, 0);
}

// ---------------- bf16 MFMA GEMM (x_proj only) -------------------------------
template<int KT, bool WITH_BN>
__global__ __launch_bounds__(256, 2)
void mfma_gemm(const u16* A, const u16* Bt,
               const float* __restrict__ bias,
               const float* __restrict__ gamma, const float* __restrict__ beta,
               const float* __restrict__ mean,  const float* __restrict__ var,
               u16* Cout, int M)
{
    __shared__ u16 smem[24576];
    u16* sA = smem;
    u16* sB = smem + 8192;

    const int tid  = threadIdx.x;
    const int lane = tid & 63;
    const int wv   = tid >> 6;
    const int lrow = lane & 15;
    const int g    = lane >> 4;
    const int m0   = blockIdx.x * 128;
    const int ldab = KT * 128;
    const int lsub = lane >> 3;
    const int gsw  = ((lane & 7) * 16) ^ (lsub << 4);

    f32x4 acc[8][4] = {};

    for (int kt = 0; kt < KT; ++kt) {
        #pragma unroll
        for (int i = 0; i < 4; ++i) {
            const int row = i * 32 + wv * 8 + lsub;
            g2lds16((const char*)A + (size_t)(m0 + row) * ldab + kt * 128 + gsw,
                    (char*)sA + i * 4096 + wv * 1024);
        }
        #pragma unroll
        for (int i = 0; i < 8; ++i) {
            const int row = i * 32 + wv * 8 + lsub;
            g2lds16((const char*)Bt + (size_t)row * ldab + kt * 128 + gsw,
                    (char*)sB + i * 4096 + wv * 1024);
        }
        __syncthreads();

        #pragma unroll
        for (int ks = 0; ks < 2; ++ks) {
            const int off1 = ks * 64 + 8 * g;
            const int off2 = off1 + 32;
            short8v bfrag[4];
            #pragma unroll
            for (int nb = 0; nb < 4; ++nb) {
                const int col = wv * 64 + nb * 16 + lrow;
                const int sw  = (col & 7) << 4;
                short4v lo = *(const short4v*)((const char*)sB + col * 128 + (off1 ^ sw));
                short4v hi = *(const short4v*)((const char*)sB + col * 128 + (off2 ^ sw));
                short8v b;
                b[0] = lo[0]; b[1] = lo[1]; b[2] = lo[2]; b[3] = lo[3];
                b[4] = hi[0]; b[5] = hi[1]; b[6] = hi[2]; b[7] = hi[3];
                bfrag[nb] = b;
            }
            #pragma unroll
            for (int mb = 0; mb < 8; ++mb) {
                const int row = mb * 16 + lrow;
                const int sw  = (row & 7) << 4;
                short4v lo = *(const short4v*)((const char*)sA + row * 128 + (off1 ^ sw));
                short4v hi = *(const short4v*)((const char*)sA + row * 128 + (off2 ^ sw));
                short8v a;
                a[0] = lo[0]; a[1] = lo[1]; a[2] = lo[2]; a[3] = lo[3];
                a[4] = hi[0]; a[5] = hi[1]; a[6] = hi[2]; a[7] = hi[3];
                #pragma unroll
                for (int nb = 0; nb < 4; ++nb)
                    acc[mb][nb] = __builtin_amdgcn_mfma_f32_16x16x32_bf16(a, bfrag[nb], acc[mb][nb], 0, 0, 0);
            }
        }
        __syncthreads();
    }

    #pragma unroll
    for (int mb = 0; mb < 8; ++mb) {
        #pragma unroll
        for (int r = 0; r < 4; ++r) {
            const int row = m0 + mb * 16 + g * 4 + r;
            if (row >= M) continue;
            #pragma unroll
            for (int nb = 0; nb < 4; ++nb) {
                const int col = wv * 64 + nb * 16 + lrow;
                float v = acc[mb][nb][r] + bias[col];
                if constexpr (WITH_BN)
                    v = (v - mean[col]) * (gamma[col] * rsqrtf(var[col] + BN_EPS)) + beta[col];
                v = fmaxf(v, 0.f);
                Cout[(size_t)row * HID + col] = f2bf(v);
            }
        }
    }
}

// ---------------- fused MLP: h = relu(BN(relu(z@W1+b1)@W2+b2)) ---------------
// Weights in FRAGMENT-PACKED global layout (Wp), read directly from L2 — no
// LDS staging, no weight barriers. LDS holds only z (staged once, 32KB) then
// y (same buffer, 520B pitch). 3 barriers/block total.
__global__ __launch_bounds__(256, 3)
void fused_mlp(const u16* __restrict__ Z, const u16* __restrict__ W1p,
               const u16* __restrict__ W2p,
               const float* __restrict__ b1,
               const float* __restrict__ scale2, const float* __restrict__ shift2,
               u16* __restrict__ Hout, int M)
{
    __shared__ u16 smem[16640];           // 33.3 KB: z (first 32KB) then y (520B pitch)
    u16* sZ = smem;
    u16* sY = smem;

    const int tid  = threadIdx.x;
    const int lane = tid & 63;
    const int wv   = tid >> 6;
    const int lrow = lane & 15;
    const int g    = lane >> 4;
    const int m0   = blockIdx.x * 64;
    const int lsub = lane >> 3;
    const int gsw  = ((lane & 7) * 16) ^ (lsub << 4);

    // ---- stage entire z tile (4 chunks of [64 rows][128B], swizzled image) ----
    #pragma unroll
    for (int kt = 0; kt < 4; ++kt) {
        #pragma unroll
        for (int i = 0; i < 2; ++i) {
            const int row = i * 32 + wv * 8 + lsub;
            g2lds16((const char*)Z + (size_t)(m0 + row) * 512 + kt * 128 + gsw,
                    (char*)sZ + kt * 8192 + i * 4096 + wv * 1024);
        }
    }
    __syncthreads();                      // barrier 1: z resident

    // ---- GEMM1: acc = z @ W1 (B-fragments straight from L2) ----
    f32x4 acc[4][4] = {};
    #pragma unroll
    for (int kt = 0; kt < 4; ++kt) {
        #pragma unroll
        for (int ks = 0; ks < 2; ++ks) {
            const int off1 = ks * 64 + 8 * g;
            const int off2 = off1 + 32;
            short8v bfrag[4];
            #pragma unroll
            for (int nb = 0; nb < 4; ++nb) {
                const int cb = wv * 4 + nb;
                u16x4 lo = *(const u16x4*)&W1p[((((kt * 2 + ks) * 2 + 0) * 16 + cb) << 8) + lane * 4];
                u16x4 hi = *(const u16x4*)&W1p[((((kt * 2 + ks) * 2 + 1) * 16 + cb) << 8) + lane * 4];
                short8v b;
                b[0] = (short)lo[0]; b[1] = (short)lo[1]; b[2] = (short)lo[2]; b[3] = (short)lo[3];
                b[4] = (short)hi[0]; b[5] = (short)hi[1]; b[6] = (short)hi[2]; b[7] = (short)hi[3];
                bfrag[nb] = b;
            }
            #pragma unroll
            for (int mb = 0; mb < 4; ++mb) {
                const int row = mb * 16 + lrow;
                const int sw  = (row & 7) << 4;
                short4v lo = *(const short4v*)((const char*)sZ + kt * 8192 + row * 128 + (off1 ^ sw));
                short4v hi = *(const short4v*)((const char*)sZ + kt * 8192 + row * 128 + (off2 ^ sw));
                short8v a;
                a[0] = lo[0]; a[1] = lo[1]; a[2] = lo[2]; a[3] = lo[3];
                a[4] = hi[0]; a[5] = hi[1]; a[6] = hi[2]; a[7] = hi[3];
                #pragma unroll
                for (int nb = 0; nb < 4; ++nb)
                    acc[mb][nb] = __builtin_amdgcn_mfma_f32_16x16x32_bf16(a, bfrag[nb], acc[mb][nb], 0, 0, 0);
            }
        }
    }
    __syncthreads();                      // barrier 2: all z reads done

    // ---- epilogue1: y = relu(acc + b1) -> sY (520B pitch, overwrites z) ----
    float b1v[4];
    #pragma unroll
    for (int nb = 0; nb < 4; ++nb) b1v[nb] = b1[wv * 64 + nb * 16 + lrow];
    #pragma unroll
    for (int mb = 0; mb < 4; ++mb) {
        #pragma unroll
        for (int r = 0; r < 4; ++r) {
            const int row = mb * 16 + g * 4 + r;
            #pragma unroll
            for (int nb = 0; nb < 4; ++nb) {
                const int col = wv * 64 + nb * 16 + lrow;
                const float v = fmaxf(acc[mb][nb][r] + b1v[nb], 0.f);
                *(u16*)((char*)sY + row * SY_PITCH + col * 2) = f2bf(v);
            }
        }
    }
    __syncthreads();                      // barrier 3: y visible

    // ---- GEMM2: acc2 = y @ W2 (B-fragments straight from L2) ----
    f32x4 acc2[4][4] = {};
    #pragma unroll
    for (int kt2 = 0; kt2 < 4; ++kt2) {
        #pragma unroll
        for (int ks = 0; ks < 2; ++ks) {
            const int off1 = ks * 64 + 8 * g;
            const int yo1  = kt2 * 128 + off1;
            const int yo2  = yo1 + 32;
            short8v bfrag[4];
            #pragma unroll
            for (int nb = 0; nb < 4; ++nb) {
                const int cb = wv * 4 + nb;
                u16x4 lo = *(const u16x4*)&W2p[((((kt2 * 2 + ks) * 2 + 0) * 16 + cb) << 8) + lane * 4];
                u16x4 hi = *(const u16x4*)&W2p[((((kt2 * 2 + ks) * 2 + 1) * 16 + cb) << 8) + lane * 4];
                short8v b;
                b[0] = (short)lo[0]; b[1] = (short)lo[1]; b[2] = (short)lo[2]; b[3] = (short)lo[3];
                b[4] = (short)hi[0]; b[5] = (short)hi[1]; b[6] = (short)hi[2]; b[7] = (short)hi[3];
                bfrag[nb] = b;
            }
            #pragma unroll
            for (int mb = 0; mb < 4; ++mb) {
                const int row = mb * 16 + lrow;
                short4v lo = *(const short4v*)((const char*)sY + row * SY_PITCH + yo1);
                short4v hi = *(const short4v*)((const char*)sY + row * SY_PITCH + yo2);
                short8v a;
                a[0] = lo[0]; a[1] = lo[1]; a[2] = lo[2]; a[3] = lo[3];
                a[4] = hi[0]; a[5] = hi[1]; a[6] = hi[2]; a[7] = hi[3];
                #pragma unroll
                for (int nb = 0; nb < 4; ++nb)
                    acc2[mb][nb] = __builtin_amdgcn_mfma_f32_16x16x32_bf16(a, bfrag[nb], acc2[mb][nb], 0, 0, 0);
            }
        }
    }

    // ---- epilogue2: h = relu(acc2*scale2 + shift2) ----
    float scl[4], shf[4];
    #pragma unroll
    for (int nb = 0; nb < 4; ++nb) {
        const int col = wv * 64 + nb * 16 + lrow;
        scl[nb] = scale2[col];
        shf[nb] = shift2[col];
    }
    #pragma unroll
    for (int mb = 0; mb < 4; ++mb) {
        #pragma unroll
        for (int r = 0; r < 4; ++r) {
            const int row = m0 + mb * 16 + g * 4 + r;
            if (row >= M) continue;
            #pragma unroll
            for (int nb = 0; nb < 4; ++nb) {
                const int col = wv * 64 + nb * 16 + lrow;
                const float v = fmaxf(acc2[mb][nb][r] * scl[nb] + shf[nb], 0.f);
                Hout[(size_t)row * HID + col] = f2bf(v);
            }
        }
    }
}

// ------- weight convert into MFMA-fragment-packed order ----------------------
__global__ __launch_bounds__(256)
void convw_kernel(const float* __restrict__ W, u16* __restrict__ Wp)
{
    size_t i = (size_t)blockIdx.x * 256 + threadIdx.x;   // 8 mats x 65536
    const int mat  = (int)(i >> 16);
    const int r    = (int)(i & 65535);
    const int j    = r & 3;
    const int lane = (r >> 2) & 63;
    const int cb   = (r >> 8) & 15;
    const int half = (r >> 12) & 1;
    const int ks   = (r >> 13) & 1;
    const int kt   = (r >> 14) & 3;
    const int col = cb * 16 + (lane & 15);
    const int k   = kt * 64 + ks * 32 + 4 * (lane >> 4) + 16 * half + j;
    Wp[i] = f2bf(W[(size_t)mat * 65536 + (size_t)k * 256 + col]);
}

__global__ __launch_bounds__(256)
void convwx_kernel(const float* __restrict__ W, u16* __restrict__ Wt)
{
    int i = blockIdx.x * 256 + threadIdx.x;
    const int n = i >> 6, k = i & 63;
    Wt[i] = (k < NODE_IN) ? f2bf(W[(size_t)k * HID + n]) : (u16)0;
}

__global__ __launch_bounds__(256)
void convx_kernel(const float* __restrict__ x, u16* __restrict__ xbf)
{
    size_t i = (size_t)blockIdx.x * 256 + threadIdx.x;
    if (i >= (size_t)N_NODES * 64) return;
    const int n = (int)(i >> 6), k = (int)(i & 63);
    xbf[i] = (k < NODE_IN) ? f2bf(x[(size_t)n * NODE_IN + k]) : (u16)0;
}

__global__ __launch_bounds__(256)
void bnfold_kernel(const float* __restrict__ b2, const float* __restrict__ gamma,
                   const float* __restrict__ beta, const float* __restrict__ mean,
                   const float* __restrict__ var,
                   float* __restrict__ scale, float* __restrict__ shift)
{
    int i = blockIdx.x * 256 + threadIdx.x;
    if (i >= NLAYERS * HID) return;
    const float s = gamma[i] * rsqrtf(var[i] + BN_EPS);
    scale[i] = s;
    shift[i] = (b2[i] - mean[i]) * s + beta[i];
}

// ---------------- CSR build --------------------------------------------------
__global__ __launch_bounds__(256)
void deg_count_kernel(const int* __restrict__ dst, int* __restrict__ deg, int E)
{
    int e = blockIdx.x * 256 + threadIdx.x;
    if (e < E) atomicAdd(&deg[dst[e]], 1);
}

__global__ __launch_bounds__(256)
void scan1_kernel(const int* __restrict__ deg, int* __restrict__ rowptr,
                  int* __restrict__ bsum, int n)
{
    __shared__ int s[256];
    const int tid = threadIdx.x;
    const int i = blockIdx.x * 256 + tid;
    const int v = (i < n) ? deg[i] : 0;
    s[tid] = v;
    __syncthreads();
    #pragma unroll
    for (int d = 1; d < 256; d <<= 1) {
        int t = (tid >= d) ? s[tid - d] : 0;
        __syncthreads();
        s[tid] += t;
        __syncthreads();
    }
    if (i < n) rowptr[i] = s[tid] - v;
    if (tid == 255) bsum[blockIdx.x] = s[255];
}

__global__ void scan2_kernel(int* bsum, int nb, int* rowptr, int n)
{
    if (threadIdx.x == 0 && blockIdx.x == 0) {
        int run = 0;
        for (int j = 0; j < nb; ++j) { int t = bsum[j]; bsum[j] = run; run += t; }
        rowptr[n] = run;
    }
}

__global__ __launch_bounds__(256)
void scan3_kernel(int* __restrict__ rowptr, const int* __restrict__ bsum, int n)
{
    int i = blockIdx.x * 256 + threadIdx.x;
    if (i < n) rowptr[i] += bsum[i >> 8];
}

__global__ __launch_bounds__(256)
void scatter_kernel(const int* __restrict__ src, const int* __restrict__ dst,
                    const float* __restrict__ ea,
                    const int* __restrict__ rowptr, int* __restrict__ fill,
                    int* __restrict__ esrc, u16* __restrict__ eap, int E)
{
    int e = blockIdx.x * 256 + threadIdx.x;
    if (e >= E) return;
    const int d = dst[e];
    const int pos = rowptr[d] + atomicAdd(&fill[d], 1);
    esrc[pos] = src[e];
    const float4 a0 = *(const float4*)&ea[(size_t)e * EDGE_IN];
    const float4 a1 = *(const float4*)&ea[(size_t)e * EDGE_IN + 4];
    u16x4 p0, p1;
    p0[0] = f2bf(a0.x); p0[1] = f2bf(a0.y); p0[2] = f2bf(a0.z); p0[3] = f2bf(a0.w);
    p1[0] = f2bf(a1.x); p1[1] = f2bf(a1.y); p1[2] = f2bf(a1.z); p1[3] = f2bf(a1.w);
    *(u16x4*)&eap[(size_t)pos * EDGE_IN]     = p0;
    *(u16x4*)&eap[(size_t)pos * EDGE_IN + 4] = p1;
}

// ------- fused CSR aggregation + z: scalarized, batch-8, clamped dups --------
__global__ __launch_bounds__(256, 4)
void agg_kernel(const u16* __restrict__ h, const u16* __restrict__ eap,
                const int* __restrict__ rowptr, const int* __restrict__ esrc,
                const float* __restrict__ W, const float* __restrict__ b,
                const float* __restrict__ eps, int l, u16* __restrict__ z)
{
    const int lane  = threadIdx.x & 63;
    const int wv    = threadIdx.x >> 6;
    const int c0    = lane * 4;
    const int lofsB = lane * 8;

    f32x4 Wr[EDGE_IN];
    #pragma unroll
    for (int k = 0; k < EDGE_IN; ++k) Wr[k] = *(const f32x4*)&W[k * HID + c0];
    const f32x4 br = *(const f32x4*)&b[c0];
    const float e1 = 1.0f + eps[l];

    for (int n = blockIdx.x * 4 + wv; n < N_NODES; n += gridDim.x * 4) {
        const int beg = __builtin_amdgcn_readfirstlane(rowptr[n]);
        const int end = __builtin_amdgcn_readfirstlane(rowptr[n + 1]);
        const int end1 = end - 1;

        const u16x4 hv = *(const u16x4*)&h[(size_t)n * HID + c0];
        float a0 = e1 * bf2f(hv[0]), a1 = e1 * bf2f(hv[1]);
        float a2 = e1 * bf2f(hv[2]), a3 = e1 * bf2f(hv[3]);

        for (int i0 = beg; i0 < end; i0 += 8) {
            int idx[8];
            #pragma unroll
            for (int j = 0; j < 8; ++j)
                idx[j] = (i0 + j < end) ? i0 + j : end1;

            // issue all index + edge-attr loads first (independent)
            int   ev_[8];
            uint4 t[8];
            #pragma unroll
            for (int j = 0; j < 8; ++j) {
                ev_[j] = esrc[idx[j]];
                t[j]   = *(const uint4*)&eap[(size_t)idx[j] * EDGE_IN];
            }
            int sb[8];
            #pragma unroll
            for (int j = 0; j < 8; ++j)
                sb[j] = __builtin_amdgcn_readfirstlane(ev_[j]) << 9;

            // 8 independent gathers in flight (clamped dups -> same line, cache hit)
            u16x4 hs[8];
            #pragma unroll
            for (int j = 0; j < 8; ++j)
                hs[j] = *(const u16x4*)((const char*)h + (unsigned)(sb[j] + lofsB));

            #pragma unroll
            for (int j = 0; j < 8; ++j) {
                if (i0 + j < end) {     // wave-uniform scalar branch
                    const unsigned dx = __builtin_amdgcn_readfirstlane((int)t[j].x);
                    const unsigned dy = __builtin_amdgcn_readfirstlane((int)t[j].y);
                    const unsigned dz = __builtin_amdgcn_readfirstlane((int)t[j].z);
                    const unsigned dw = __builtin_amdgcn_readfirstlane((int)t[j].w);
                    f32x4 evv = br;
                    evv += lo_f(dx) * Wr[0];
                    evv += hi_f(dx) * Wr[1];
                    evv += lo_f(dy) * Wr[2];
                    evv += hi_f(dy) * Wr[3];
                    evv += lo_f(dz) * Wr[4];
                    evv += hi_f(dz) * Wr[5];
                    evv += lo_f(dw) * Wr[6];
                    evv += hi_f(dw) * Wr[7];
                    a0 += fmaxf(bf2f(hs[j][0]) + evv[0], 0.f);
                    a1 += fmaxf(bf2f(hs[j][1]) + evv[1], 0.f);
                    a2 += fmaxf(bf2f(hs[j][2]) + evv[2], 0.f);
                    a3 += fmaxf(bf2f(hs[j][3]) + evv[3], 0.f);
                }
            }
        }
        u16x4 o;
        o[0] = f2bf(a0); o[1] = f2bf(a1); o[2] = f2bf(a2); o[3] = f2bf(a3);
        *(u16x4*)&z[(size_t)n * HID + c0] = o;
    }
}

// ------- pool: wave-per-node-stripe, vectorized u16x4 loads ------------------
__global__ __launch_bounds__(256)
void pool_kernel(const u16* __restrict__ h, const int* __restrict__ batch,
                 float* __restrict__ gsum, int* __restrict__ cnt, int n)
{
    const int lane = threadIdx.x & 63;
    const int wv   = threadIdx.x >> 6;
    const int c0   = lane * 4;
    const int n0   = blockIdx.x * 64;

    f32x4 acc = {0.f, 0.f, 0.f, 0.f};
    int gcur = -1;
    int c = 0;

    for (int i = wv; i < 64; i += 4) {
        const int node = n0 + i;
        if (node >= n) break;
        const int g = __builtin_amdgcn_readfirstlane(batch[node]);
        if (g != gcur) {
            if (gcur >= 0) {
                atomicAdd(&gsum[gcur * HID + c0 + 0], acc[0]);
                atomicAdd(&gsum[gcur * HID + c0 + 1], acc[1]);
                atomicAdd(&gsum[gcur * HID + c0 + 2], acc[2]);
                atomicAdd(&gsum[gcur * HID + c0 + 3], acc[3]);
                if (lane == 0) atomicAdd(&cnt[gcur], c);
            }
            acc = (f32x4){0.f, 0.f, 0.f, 0.f};
            c = 0;
            gcur = g;
        }
        const u16x4 hv = *(const u16x4*)&h[(size_t)node * HID + c0];
        acc[0] += bf2f(hv[0]);
        acc[1] += bf2f(hv[1]);
        acc[2] += bf2f(hv[2]);
        acc[3] += bf2f(hv[3]);
        c++;
    }
    if (gcur >= 0) {
        atomicAdd(&gsum[gcur * HID + c0 + 0], acc[0]);
        atomicAdd(&gsum[gcur * HID + c0 + 1], acc[1]);
        atomicAdd(&gsum[gcur * HID + c0 + 2], acc[2]);
        atomicAdd(&gsum[gcur * HID + c0 + 3], acc[3]);
        if (lane == 0) atomicAdd(&cnt[gcur], c);
    }
}

__global__ __launch_bounds__(128)
void head_kernel(const float* __restrict__ gsum, const int* __restrict__ cnt,
                 const float* __restrict__ W1, const float* __restrict__ b1,
                 const float* __restrict__ W2, const float* __restrict__ b2,
                 float* __restrict__ out)
{
    const int gi = blockIdx.x;
    const int j = threadIdx.x;
    __shared__ float gs[HID];
    __shared__ float red[128];

    const float c = fmaxf((float)cnt[gi], 1.0f);
    gs[j]       = gsum[gi * HID + j] / c;
    gs[j + 128] = gsum[gi * HID + 128 + j] / c;
    __syncthreads();

    float acc = b1[j];
    #pragma unroll 8
    for (int k = 0; k < HID; ++k) acc += gs[k] * W1[k * 128 + j];
    acc = fmaxf(acc, 0.f);
    red[j] = acc * W2[j];
    __syncthreads();
    for (int s = 64; s > 0; s >>= 1) {
        if (j < s) red[j] += red[j + s];
        __syncthreads();
    }
    if (j == 0) out[gi] = red[0] + b2[0];
}

extern "C" void kernel_launch(void* const* d_in, const int* in_sizes, int n_in,
                              void* d_out, int out_size, void* d_ws, size_t ws_size,
                              hipStream_t stream)
{
    const float* x         = (const float*)d_in[0];
    const int*   ei        = (const int*)d_in[1];
    const float* edge_attr = (const float*)d_in[2];
    const int*   batch     = (const int*)d_in[3];
    const float* xproj_W   = (const float*)d_in[4];
    const float* xproj_b   = (const float*)d_in[5];
    const float* xp_gamma  = (const float*)d_in[6];
    const float* xp_beta   = (const float*)d_in[7];
    const float* xp_mean   = (const float*)d_in[8];
    const float* xp_var    = (const float*)d_in[9];
    const float* edge_W    = (const float*)d_in[10];
    const float* edge_b    = (const float*)d_in[11];
    const float* mlp_W1    = (const float*)d_in[12];
    const float* mlp_b1    = (const float*)d_in[13];
    const float* mlp_W2    = (const float*)d_in[14];
    const float* mlp_b2    = (const float*)d_in[15];
    const float* eps       = (const float*)d_in[16];
    const float* bn_gamma  = (const float*)d_in[17];
    const float* bn_beta   = (const float*)d_in[18];
    const float* bn_mean   = (const float*)d_in[19];
    const float* bn_var    = (const float*)d_in[20];
    const float* head_W1   = (const float*)d_in[21];
    const float* head_b1   = (const float*)d_in[22];
    const float* head_W2   = (const float*)d_in[23];
    const float* head_b2   = (const float*)d_in[24];
    float* out = (float*)d_out;

    const int* srcI = ei;
    const int* dstI = ei + N_EDGES;

    // ---- workspace layout ----
    char* w = (char*)d_ws;
    u16*   h      = (u16*)w;                 w += (size_t)N_NODES * HID * 2;   // 51.2 MB
    u16*   zy     = (u16*)w;                 w += (size_t)N_NODES * HID * 2;   // 51.2 MB
    u16*   xbf    = (u16*)w;                 w += (size_t)N_NODES * 64 * 2;    // 12.8 MB
    u16*   Wp1    = (u16*)w;                 w += (size_t)NLAYERS * 65536 * 2;
    u16*   Wp2    = (u16*)w;                 w += (size_t)NLAYERS * 65536 * 2;
    u16*   Wxt    = (u16*)w;                 w += 16384 * 2;
    float* scale2 = (float*)w;               w += NLAYERS * HID * 4;
    float* shift2 = (float*)w;               w += NLAYERS * HID * 4;
    int*   rowptr = (int*)w;                 w += 100032 * 4;
    int*   deg    = (int*)w;                 w += 100032 * 4;
    int*   fill   = (int*)w;                 w += 100032 * 4;
    int*   bsum   = (int*)w;                 w += 512 * 4;
    int*   esrc   = (int*)w;                 w += (size_t)N_EDGES * 4;
    u16*   eap    = (u16*)w;                 w += (size_t)N_EDGES * EDGE_IN * 2; // 8 MB
    float* gsum   = (float*)w;               w += NGRAPH * HID * 4;
    int*   cnt    = (int*)w;                 w += NGRAPH * 4;

    // ---- one-time prep ----
    convw_kernel<<<2048, 256, 0, stream>>>(mlp_W1, Wp1);
    convw_kernel<<<2048, 256, 0, stream>>>(mlp_W2, Wp2);
    convwx_kernel<<<64, 256, 0, stream>>>(xproj_W, Wxt);
    convx_kernel<<<25000, 256, 0, stream>>>(x, xbf);
    bnfold_kernel<<<8, 256, 0, stream>>>(mlp_b2, bn_gamma, bn_beta, bn_mean, bn_var,
                                         scale2, shift2);

    hipMemsetAsync(deg, 0, 2 * 100032 * sizeof(int), stream);  // deg + fill (adjacent)
    deg_count_kernel<<<(N_EDGES + 255) / 256, 256, 0, stream>>>(dstI, deg, N_EDGES);
    scan1_kernel<<<391, 256, 0, stream>>>(deg, rowptr, bsum, N_NODES);
    scan2_kernel<<<1, 64, 0, stream>>>(bsum, 391, rowptr, N_NODES);
    scan3_kernel<<<391, 256, 0, stream>>>(rowptr, bsum, N_NODES);
    scatter_kernel<<<(N_EDGES + 255) / 256, 256, 0, stream>>>(
        srcI, dstI, edge_attr, rowptr, fill, esrc, eap, N_EDGES);

    // ---- x_proj ----
    mfma_gemm<1, true><<<(N_NODES + 127) / 128, 256, 0, stream>>>(
        xbf, Wxt, xproj_b, xp_gamma, xp_beta, xp_mean, xp_var, h, N_NODES);

    const int fgrid = (N_NODES + 63) / 64;
    for (int l = 0; l < NLAYERS; ++l) {
        agg_kernel<<<2048, 256, 0, stream>>>(
            h, eap, rowptr, esrc,
            edge_W + (size_t)l * EDGE_IN * HID, edge_b + (size_t)l * HID,
            eps, l, zy);
        fused_mlp<<<fgrid, 256, 0, stream>>>(
            zy, Wp1 + (size_t)l * 65536, Wp2 + (size_t)l * 65536,
            mlp_b1 + (size_t)l * HID, scale2 + (size_t)l * HID, shift2 + (size_t)l * HID,
            h, N_NODES);
    }

    hipMemsetAsync(gsum, 0, (NGRAPH * HID + NGRAPH) * sizeof(float), stream);
    pool_kernel<<<(N_NODES + 63) / 64, 256, 0, stream>>>(h, batch, gsum, cnt, N_NODES);
    head_kernel<<<NGRAPH, 128, 0, stream>>>(gsum, cnt, head_W1, head_b1, head_W2, head_b2, out);
}

// Round 17
// 1062.767 us; speedup vs baseline: 1.0758x; 1.0758x over previous
//
#include <hip/hip_runtime.h>

#define N_NODES 100000
#define N_EDGES 500000
#define NODE_IN 60
#define EDGE_IN 8
#define HID 256
#define NLAYERS 8
#define NGRAPH 64
#define BN_EPS 1e-5f
#define SY_PITCH 520   // 512 + 8: breaks the all-rows-bank-0 alignment, keeps 8B align

typedef __attribute__((ext_vector_type(4))) float f32x4;
typedef __attribute__((ext_vector_type(4))) short short4v;
typedef __attribute__((ext_vector_type(8))) short short8v;
typedef __attribute__((ext_vector_type(4))) unsigned short u16x4;
typedef unsigned short u16;

__device__ __forceinline__ u16 f2bf(float f) {
    unsigned int u = __builtin_bit_cast(unsigned int, f);
    u += 0x7fffu + ((u >> 16) & 1u);
    return (u16)(u >> 16);
}
__device__ __forceinline__ float bf2f(u16 u) {
    unsigned int x = ((unsigned int)u) << 16;
    return __builtin_bit_cast(float, x);
}
__device__ __forceinline__ float lo_f(unsigned int d) {
    return __builtin_bit_cast(float, d << 16);
}
__device__ __forceinline__ float hi_f(unsigned int d) {
    return __builtin_bit_cast(float, d & 0xffff0000u);
}

// async global->LDS, 16B per lane; lds dest = wave-uniform base + lane*16
__device__ __forceinline__ void g2lds16(const void* g, void* l) {
    __builtin_amdgcn_global_load_lds(
        (const __attribute__((address_space(1))) void*)g,
        (__attribute__((address_space(3))) void*)l, 16, 0, 0);
}

// ---------------- bf16 MFMA GEMM (x_proj only) -------------------------------
template<int KT, bool WITH_BN>
__global__ __launch_bounds__(256, 2)
void mfma_gemm(const u16* A, const u16* Bt,
               const float* __restrict__ bias,
               const float* __restrict__ gamma, const float* __restrict__ beta,
               const float* __restrict__ mean,  const float* __restrict__ var,
               u16* Cout, int M)
{
    __shared__ u16 smem[24576];
    u16* sA = smem;
    u16* sB = smem + 8192;

    const int tid  = threadIdx.x;
    const int lane = tid & 63;
    const int wv   = tid >> 6;
    const int lrow = lane & 15;
    const int g    = lane >> 4;
    const int m0   = blockIdx.x * 128;
    const int ldab = KT * 128;
    const int lsub = lane >> 3;
    const int gsw  = ((lane & 7) * 16) ^ (lsub << 4);

    f32x4 acc[8][4] = {};

    for (int kt = 0; kt < KT; ++kt) {
        #pragma unroll
        for (int i = 0; i < 4; ++i) {
            const int row = i * 32 + wv * 8 + lsub;
            g2lds16((const char*)A + (size_t)(m0 + row) * ldab + kt * 128 + gsw,
                    (char*)sA + i * 4096 + wv * 1024);
        }
        #pragma unroll
        for (int i = 0; i < 8; ++i) {
            const int row = i * 32 + wv * 8 + lsub;
            g2lds16((const char*)Bt + (size_t)row * ldab + kt * 128 + gsw,
                    (char*)sB + i * 4096 + wv * 1024);
        }
        __syncthreads();

        #pragma unroll
        for (int ks = 0; ks < 2; ++ks) {
            const int off1 = ks * 64 + 8 * g;
            const int off2 = off1 + 32;
            short8v bfrag[4];
            #pragma unroll
            for (int nb = 0; nb < 4; ++nb) {
                const int col = wv * 64 + nb * 16 + lrow;
                const int sw  = (col & 7) << 4;
                short4v lo = *(const short4v*)((const char*)sB + col * 128 + (off1 ^ sw));
                short4v hi = *(const short4v*)((const char*)sB + col * 128 + (off2 ^ sw));
                short8v b;
                b[0] = lo[0]; b[1] = lo[1]; b[2] = lo[2]; b[3] = lo[3];
                b[4] = hi[0]; b[5] = hi[1]; b[6] = hi[2]; b[7] = hi[3];
                bfrag[nb] = b;
            }
            #pragma unroll
            for (int mb = 0; mb < 8; ++mb) {
                const int row = mb * 16 + lrow;
                const int sw  = (row & 7) << 4;
                short4v lo = *(const short4v*)((const char*)sA + row * 128 + (off1 ^ sw));
                short4v hi = *(const short4v*)((const char*)sA + row * 128 + (off2 ^ sw));
                short8v a;
                a[0] = lo[0]; a[1] = lo[1]; a[2] = lo[2]; a[3] = lo[3];
                a[4] = hi[0]; a[5] = hi[1]; a[6] = hi[2]; a[7] = hi[3];
                #pragma unroll
                for (int nb = 0; nb < 4; ++nb)
                    acc[mb][nb] = __builtin_amdgcn_mfma_f32_16x16x32_bf16(a, bfrag[nb], acc[mb][nb], 0, 0, 0);
            }
        }
        __syncthreads();
    }

    #pragma unroll
    for (int mb = 0; mb < 8; ++mb) {
        #pragma unroll
        for (int r = 0; r < 4; ++r) {
            const int row = m0 + mb * 16 + g * 4 + r;
            if (row >= M) continue;
            #pragma unroll
            for (int nb = 0; nb < 4; ++nb) {
                const int col = wv * 64 + nb * 16 + lrow;
                float v = acc[mb][nb][r] + bias[col];
                if constexpr (WITH_BN)
                    v = (v - mean[col]) * (gamma[col] * rsqrtf(var[col] + BN_EPS)) + beta[col];
                v = fmaxf(v, 0.f);
                Cout[(size_t)row * HID + col] = f2bf(v);
            }
        }
    }
}

// ---------------- fused MLP: h = relu(BN(relu(z@W1+b1)@W2+b2)) ---------------
// Weights in FRAGMENT-PACKED global layout (Wp), read directly from L2 — no
// LDS staging, no weight barriers. LDS holds only z (staged once, 32KB) then
// y (same buffer, 520B pitch). 3 barriers/block total.
__global__ __launch_bounds__(256, 3)
void fused_mlp(const u16* __restrict__ Z, const u16* __restrict__ W1p,
               const u16* __restrict__ W2p,
               const float* __restrict__ b1,
               const float* __restrict__ scale2, const float* __restrict__ shift2,
               u16* __restrict__ Hout, int M)
{
    __shared__ u16 smem[16640];           // 33.3 KB: z (first 32KB) then y (520B pitch)
    u16* sZ = smem;
    u16* sY = smem;

    const int tid  = threadIdx.x;
    const int lane = tid & 63;
    const int wv   = tid >> 6;
    const int lrow = lane & 15;
    const int g    = lane >> 4;
    const int m0   = blockIdx.x * 64;
    const int lsub = lane >> 3;
    const int gsw  = ((lane & 7) * 16) ^ (lsub << 4);

    // ---- stage entire z tile (4 chunks of [64 rows][128B], swizzled image) ----
    #pragma unroll
    for (int kt = 0; kt < 4; ++kt) {
        #pragma unroll
        for (int i = 0; i < 2; ++i) {
            const int row = i * 32 + wv * 8 + lsub;
            g2lds16((const char*)Z + (size_t)(m0 + row) * 512 + kt * 128 + gsw,
                    (char*)sZ + kt * 8192 + i * 4096 + wv * 1024);
        }
    }
    __syncthreads();                      // barrier 1: z resident

    // ---- GEMM1: acc = z @ W1 (B-fragments straight from L2) ----
    f32x4 acc[4][4] = {};
    #pragma unroll
    for (int kt = 0; kt < 4; ++kt) {
        #pragma unroll
        for (int ks = 0; ks < 2; ++ks) {
            const int off1 = ks * 64 + 8 * g;
            const int off2 = off1 + 32;
            short8v bfrag[4];
            #pragma unroll
            for (int nb = 0; nb < 4; ++nb) {
                const int cb = wv * 4 + nb;
                u16x4 lo = *(const u16x4*)&W1p[((((kt * 2 + ks) * 2 + 0) * 16 + cb) << 8) + lane * 4];
                u16x4 hi = *(const u16x4*)&W1p[((((kt * 2 + ks) * 2 + 1) * 16 + cb) << 8) + lane * 4];
                short8v b;
                b[0] = (short)lo[0]; b[1] = (short)lo[1]; b[2] = (short)lo[2]; b[3] = (short)lo[3];
                b[4] = (short)hi[0]; b[5] = (short)hi[1]; b[6] = (short)hi[2]; b[7] = (short)hi[3];
                bfrag[nb] = b;
            }
            #pragma unroll
            for (int mb = 0; mb < 4; ++mb) {
                const int row = mb * 16 + lrow;
                const int sw  = (row & 7) << 4;
                short4v lo = *(const short4v*)((const char*)sZ + kt * 8192 + row * 128 + (off1 ^ sw));
                short4v hi = *(const short4v*)((const char*)sZ + kt * 8192 + row * 128 + (off2 ^ sw));
                short8v a;
                a[0] = lo[0]; a[1] = lo[1]; a[2] = lo[2]; a[3] = lo[3];
                a[4] = hi[0]; a[5] = hi[1]; a[6] = hi[2]; a[7] = hi[3];
                #pragma unroll
                for (int nb = 0; nb < 4; ++nb)
                    acc[mb][nb] = __builtin_amdgcn_mfma_f32_16x16x32_bf16(a, bfrag[nb], acc[mb][nb], 0, 0, 0);
            }
        }
    }
    __syncthreads();                      // barrier 2: all z reads done

    // ---- epilogue1: y = relu(acc + b1) -> sY (520B pitch, overwrites z) ----
    float b1v[4];
    #pragma unroll
    for (int nb = 0; nb < 4; ++nb) b1v[nb] = b1[wv * 64 + nb * 16 + lrow];
    #pragma unroll
    for (int mb = 0; mb < 4; ++mb) {
        #pragma unroll
        for (int r = 0; r < 4; ++r) {
            const int row = mb * 16 + g * 4 + r;
            #pragma unroll
            for (int nb = 0; nb < 4; ++nb) {
                const int col = wv * 64 + nb * 16 + lrow;
                const float v = fmaxf(acc[mb][nb][r] + b1v[nb], 0.f);
                *(u16*)((char*)sY + row * SY_PITCH + col * 2) = f2bf(v);
            }
        }
    }
    __syncthreads();                      // barrier 3: y visible

    // ---- GEMM2: acc2 = y @ W2 (B-fragments straight from L2) ----
    f32x4 acc2[4][4] = {};
    #pragma unroll
    for (int kt2 = 0; kt2 < 4; ++kt2) {
        #pragma unroll
        for (int ks = 0; ks < 2; ++ks) {
            const int off1 = ks * 64 + 8 * g;
            const int yo1  = kt2 * 128 + off1;
            const int yo2  = yo1 + 32;
            short8v bfrag[4];
            #pragma unroll
            for (int nb = 0; nb < 4; ++nb) {
                const int cb = wv * 4 + nb;
                u16x4 lo = *(const u16x4*)&W2p[((((kt2 * 2 + ks) * 2 + 0) * 16 + cb) << 8) + lane * 4];
                u16x4 hi = *(const u16x4*)&W2p[((((kt2 * 2 + ks) * 2 + 1) * 16 + cb) << 8) + lane * 4];
                short8v b;
                b[0] = (short)lo[0]; b[1] = (short)lo[1]; b[2] = (short)lo[2]; b[3] = (short)lo[3];
                b[4] = (short)hi[0]; b[5] = (short)hi[1]; b[6] = (short)hi[2]; b[7] = (short)hi[3];
                bfrag[nb] = b;
            }
            #pragma unroll
            for (int mb = 0; mb < 4; ++mb) {
                const int row = mb * 16 + lrow;
                short4v lo = *(const short4v*)((const char*)sY + row * SY_PITCH + yo1);
                short4v hi = *(const short4v*)((const char*)sY + row * SY_PITCH + yo2);
                short8v a;
                a[0] = lo[0]; a[1] = lo[1]; a[2] = lo[2]; a[3] = lo[3];
                a[4] = hi[0]; a[5] = hi[1]; a[6] = hi[2]; a[7] = hi[3];
                #pragma unroll
                for (int nb = 0; nb < 4; ++nb)
                    acc2[mb][nb] = __builtin_amdgcn_mfma_f32_16x16x32_bf16(a, bfrag[nb], acc2[mb][nb], 0, 0, 0);
            }
        }
    }

    // ---- epilogue2: h = relu(acc2*scale2 + shift2) ----
    float scl[4], shf[4];
    #pragma unroll
    for (int nb = 0; nb < 4; ++nb) {
        const int col = wv * 64 + nb * 16 + lrow;
        scl[nb] = scale2[col];
        shf[nb] = shift2[col];
    }
    #pragma unroll
    for (int mb = 0; mb < 4; ++mb) {
        #pragma unroll
        for (int r = 0; r < 4; ++r) {
            const int row = m0 + mb * 16 + g * 4 + r;
            if (row >= M) continue;
            #pragma unroll
            for (int nb = 0; nb < 4; ++nb) {
                const int col = wv * 64 + nb * 16 + lrow;
                const float v = fmaxf(acc2[mb][nb][r] * scl[nb] + shf[nb], 0.f);
                Hout[(size_t)row * HID + col] = f2bf(v);
            }
        }
    }
}

// ------- weight convert into MFMA-fragment-packed order ----------------------
__global__ __launch_bounds__(256)
void convw_kernel(const float* __restrict__ W, u16* __restrict__ Wp)
{
    size_t i = (size_t)blockIdx.x * 256 + threadIdx.x;   // 8 mats x 65536
    const int mat  = (int)(i >> 16);
    const int r    = (int)(i & 65535);
    const int j    = r & 3;
    const int lane = (r >> 2) & 63;
    const int cb   = (r >> 8) & 15;
    const int half = (r >> 12) & 1;
    const int ks   = (r >> 13) & 1;
    const int kt   = (r >> 14) & 3;
    const int col = cb * 16 + (lane & 15);
    const int k   = kt * 64 + ks * 32 + 4 * (lane >> 4) + 16 * half + j;
    Wp[i] = f2bf(W[(size_t)mat * 65536 + (size_t)k * 256 + col]);
}

__global__ __launch_bounds__(256)
void convwx_kernel(const float* __restrict__ W, u16* __restrict__ Wt)
{
    int i = blockIdx.x * 256 + threadIdx.x;
    const int n = i >> 6, k = i & 63;
    Wt[i] = (k < NODE_IN) ? f2bf(W[(size_t)k * HID + n]) : (u16)0;
}

__global__ __launch_bounds__(256)
void convx_kernel(const float* __restrict__ x, u16* __restrict__ xbf)
{
    size_t i = (size_t)blockIdx.x * 256 + threadIdx.x;
    if (i >= (size_t)N_NODES * 64) return;
    const int n = (int)(i >> 6), k = (int)(i & 63);
    xbf[i] = (k < NODE_IN) ? f2bf(x[(size_t)n * NODE_IN + k]) : (u16)0;
}

__global__ __launch_bounds__(256)
void bnfold_kernel(const float* __restrict__ b2, const float* __restrict__ gamma,
                   const float* __restrict__ beta, const float* __restrict__ mean,
                   const float* __restrict__ var,
                   float* __restrict__ scale, float* __restrict__ shift)
{
    int i = blockIdx.x * 256 + threadIdx.x;
    if (i >= NLAYERS * HID) return;
    const float s = gamma[i] * rsqrtf(var[i] + BN_EPS);
    scale[i] = s;
    shift[i] = (b2[i] - mean[i]) * s + beta[i];
}

// ---------------- CSR build --------------------------------------------------
__global__ __launch_bounds__(256)
void deg_count_kernel(const int* __restrict__ dst, int* __restrict__ deg, int E)
{
    int e = blockIdx.x * 256 + threadIdx.x;
    if (e < E) atomicAdd(&deg[dst[e]], 1);
}

__global__ __launch_bounds__(256)
void scan1_kernel(const int* __restrict__ deg, int* __restrict__ rowptr,
                  int* __restrict__ bsum, int n)
{
    __shared__ int s[256];
    const int tid = threadIdx.x;
    const int i = blockIdx.x * 256 + tid;
    const int v = (i < n) ? deg[i] : 0;
    s[tid] = v;
    __syncthreads();
    #pragma unroll
    for (int d = 1; d < 256; d <<= 1) {
        int t = (tid >= d) ? s[tid - d] : 0;
        __syncthreads();
        s[tid] += t;
        __syncthreads();
    }
    if (i < n) rowptr[i] = s[tid] - v;
    if (tid == 255) bsum[blockIdx.x] = s[255];
}

__global__ void scan2_kernel(int* bsum, int nb, int* rowptr, int n)
{
    if (threadIdx.x == 0 && blockIdx.x == 0) {
        int run = 0;
        for (int j = 0; j < nb; ++j) { int t = bsum[j]; bsum[j] = run; run += t; }
        rowptr[n] = run;
    }
}

__global__ __launch_bounds__(256)
void scan3_kernel(int* __restrict__ rowptr, const int* __restrict__ bsum, int n)
{
    int i = blockIdx.x * 256 + threadIdx.x;
    if (i < n) rowptr[i] += bsum[i >> 8];
}

__global__ __launch_bounds__(256)
void scatter_kernel(const int* __restrict__ src, const int* __restrict__ dst,
                    const float* __restrict__ ea,
                    const int* __restrict__ rowptr, int* __restrict__ fill,
                    int* __restrict__ esrc, u16* __restrict__ eap, int E)
{
    int e = blockIdx.x * 256 + threadIdx.x;
    if (e >= E) return;
    const int d = dst[e];
    const int pos = rowptr[d] + atomicAdd(&fill[d], 1);
    esrc[pos] = src[e];
    const float4 a0 = *(const float4*)&ea[(size_t)e * EDGE_IN];
    const float4 a1 = *(const float4*)&ea[(size_t)e * EDGE_IN + 4];
    u16x4 p0, p1;
    p0[0] = f2bf(a0.x); p0[1] = f2bf(a0.y); p0[2] = f2bf(a0.z); p0[3] = f2bf(a0.w);
    p1[0] = f2bf(a1.x); p1[1] = f2bf(a1.y); p1[2] = f2bf(a1.z); p1[3] = f2bf(a1.w);
    *(u16x4*)&eap[(size_t)pos * EDGE_IN]     = p0;
    *(u16x4*)&eap[(size_t)pos * EDGE_IN + 4] = p1;
}

// ------- fused CSR aggregation + z: scalarized indices + edge attrs ----------
__global__ __launch_bounds__(256, 8)
void agg_kernel(const u16* __restrict__ h, const u16* __restrict__ eap,
                const int* __restrict__ rowptr, const int* __restrict__ esrc,
                const float* __restrict__ W, const float* __restrict__ b,
                const float* __restrict__ eps, int l, u16* __restrict__ z)
{
    const int lane  = threadIdx.x & 63;
    const int wv    = threadIdx.x >> 6;
    const int c0    = lane * 4;
    const int lofsB = lane * 8;

    f32x4 Wr[EDGE_IN];
    #pragma unroll
    for (int k = 0; k < EDGE_IN; ++k) Wr[k] = *(const f32x4*)&W[k * HID + c0];
    const f32x4 br = *(const f32x4*)&b[c0];
    const float e1 = 1.0f + eps[l];

    for (int n = blockIdx.x * 4 + wv; n < N_NODES; n += gridDim.x * 4) {
        const int beg = __builtin_amdgcn_readfirstlane(rowptr[n]);
        const int end = __builtin_amdgcn_readfirstlane(rowptr[n + 1]);
        const int end1 = end - 1;

        const u16x4 hv = *(const u16x4*)&h[(size_t)n * HID + c0];
        float a0 = e1 * bf2f(hv[0]), a1 = e1 * bf2f(hv[1]);
        float a2 = e1 * bf2f(hv[2]), a3 = e1 * bf2f(hv[3]);

        for (int i0 = beg; i0 < end; i0 += 4) {
            int idx0 = i0;
            int idx1 = (i0 + 1 < end) ? i0 + 1 : end1;
            int idx2 = (i0 + 2 < end) ? i0 + 2 : end1;
            int idx3 = (i0 + 3 < end) ? i0 + 3 : end1;

            const int sb0 = __builtin_amdgcn_readfirstlane(esrc[idx0]) << 9;
            const int sb1 = __builtin_amdgcn_readfirstlane(esrc[idx1]) << 9;
            const int sb2 = __builtin_amdgcn_readfirstlane(esrc[idx2]) << 9;
            const int sb3 = __builtin_amdgcn_readfirstlane(esrc[idx3]) << 9;

            u16x4 hs0 = *(const u16x4*)((const char*)h + (unsigned)(sb0 + lofsB));
            u16x4 hs1 = *(const u16x4*)((const char*)h + (unsigned)(sb1 + lofsB));
            u16x4 hs2 = *(const u16x4*)((const char*)h + (unsigned)(sb2 + lofsB));
            u16x4 hs3 = *(const u16x4*)((const char*)h + (unsigned)(sb3 + lofsB));

            uint4 t0 = *(const uint4*)&eap[(size_t)idx0 * EDGE_IN];
            uint4 t1 = *(const uint4*)&eap[(size_t)idx1 * EDGE_IN];
            uint4 t2 = *(const uint4*)&eap[(size_t)idx2 * EDGE_IN];
            uint4 t3 = *(const uint4*)&eap[(size_t)idx3 * EDGE_IN];

            #pragma unroll
            for (int j = 0; j < 4; ++j) {
                if (i0 + j < end) {     // wave-uniform scalar branch
                    const uint4 tt = (j == 0) ? t0 : (j == 1) ? t1 : (j == 2) ? t2 : t3;
                    const u16x4 hh = (j == 0) ? hs0 : (j == 1) ? hs1 : (j == 2) ? hs2 : hs3;
                    const unsigned dx = __builtin_amdgcn_readfirstlane((int)tt.x);
                    const unsigned dy = __builtin_amdgcn_readfirstlane((int)tt.y);
                    const unsigned dz = __builtin_amdgcn_readfirstlane((int)tt.z);
                    const unsigned dw = __builtin_amdgcn_readfirstlane((int)tt.w);
                    f32x4 ev = br;
                    ev += lo_f(dx) * Wr[0];
                    ev += hi_f(dx) * Wr[1];
                    ev += lo_f(dy) * Wr[2];
                    ev += hi_f(dy) * Wr[3];
                    ev += lo_f(dz) * Wr[4];
                    ev += hi_f(dz) * Wr[5];
                    ev += lo_f(dw) * Wr[6];
                    ev += hi_f(dw) * Wr[7];
                    a0 += fmaxf(bf2f(hh[0]) + ev[0], 0.f);
                    a1 += fmaxf(bf2f(hh[1]) + ev[1], 0.f);
                    a2 += fmaxf(bf2f(hh[2]) + ev[2], 0.f);
                    a3 += fmaxf(bf2f(hh[3]) + ev[3], 0.f);
                }
            }
        }
        u16x4 o;
        o[0] = f2bf(a0); o[1] = f2bf(a1); o[2] = f2bf(a2); o[3] = f2bf(a3);
        *(u16x4*)&z[(size_t)n * HID + c0] = o;
    }
}

// ------- pool: wave-per-node-stripe, vectorized u16x4 loads ------------------
__global__ __launch_bounds__(256)
void pool_kernel(const u16* __restrict__ h, const int* __restrict__ batch,
                 float* __restrict__ gsum, int* __restrict__ cnt, int n)
{
    const int lane = threadIdx.x & 63;
    const int wv   = threadIdx.x >> 6;
    const int c0   = lane * 4;
    const int n0   = blockIdx.x * 64;

    f32x4 acc = {0.f, 0.f, 0.f, 0.f};
    int gcur = -1;
    int c = 0;

    for (int i = wv; i < 64; i += 4) {
        const int node = n0 + i;
        if (node >= n) break;
        const int g = __builtin_amdgcn_readfirstlane(batch[node]);
        if (g != gcur) {
            if (gcur >= 0) {
                atomicAdd(&gsum[gcur * HID + c0 + 0], acc[0]);
                atomicAdd(&gsum[gcur * HID + c0 + 1], acc[1]);
                atomicAdd(&gsum[gcur * HID + c0 + 2], acc[2]);
                atomicAdd(&gsum[gcur * HID + c0 + 3], acc[3]);
                if (lane == 0) atomicAdd(&cnt[gcur], c);
            }
            acc = (f32x4){0.f, 0.f, 0.f, 0.f};
            c = 0;
            gcur = g;
        }
        const u16x4 hv = *(const u16x4*)&h[(size_t)node * HID + c0];
        acc[0] += bf2f(hv[0]);
        acc[1] += bf2f(hv[1]);
        acc[2] += bf2f(hv[2]);
        acc[3] += bf2f(hv[3]);
        c++;
    }
    if (gcur >= 0) {
        atomicAdd(&gsum[gcur * HID + c0 + 0], acc[0]);
        atomicAdd(&gsum[gcur * HID + c0 + 1], acc[1]);
        atomicAdd(&gsum[gcur * HID + c0 + 2], acc[2]);
        atomicAdd(&gsum[gcur * HID + c0 + 3], acc[3]);
        if (lane == 0) atomicAdd(&cnt[gcur], c);
    }
}

__global__ __launch_bounds__(128)
void head_kernel(const float* __restrict__ gsum, const int* __restrict__ cnt,
                 const float* __restrict__ W1, const float* __restrict__ b1,
                 const float* __restrict__ W2, const float* __restrict__ b2,
                 float* __restrict__ out)
{
    const int gi = blockIdx.x;
    const int j = threadIdx.x;
    __shared__ float gs[HID];
    __shared__ float red[128];

    const float c = fmaxf((float)cnt[gi], 1.0f);
    gs[j]       = gsum[gi * HID + j] / c;
    gs[j + 128] = gsum[gi * HID + 128 + j] / c;
    __syncthreads();

    float acc = b1[j];
    #pragma unroll 8
    for (int k = 0; k < HID; ++k) acc += gs[k] * W1[k * 128 + j];
    acc = fmaxf(acc, 0.f);
    red[j] = acc * W2[j];
    __syncthreads();
    for (int s = 64; s > 0; s >>= 1) {
        if (j < s) red[j] += red[j + s];
        __syncthreads();
    }
    if (j == 0) out[gi] = red[0] + b2[0];
}

extern "C" void kernel_launch(void* const* d_in, const int* in_sizes, int n_in,
                              void* d_out, int out_size, void* d_ws, size_t ws_size,
                              hipStream_t stream)
{
    const float* x         = (const float*)d_in[0];
    const int*   ei        = (const int*)d_in[1];
    const float* edge_attr = (const float*)d_in[2];
    const int*   batch     = (const int*)d_in[3];
    const float* xproj_W   = (const float*)d_in[4];
    const float* xproj_b   = (const float*)d_in[5];
    const float* xp_gamma  = (const float*)d_in[6];
    const float* xp_beta   = (const float*)d_in[7];
    const float* xp_mean   = (const float*)d_in[8];
    const float* xp_var    = (const float*)d_in[9];
    const float* edge_W    = (const float*)d_in[10];
    const float* edge_b    = (const float*)d_in[11];
    const float* mlp_W1    = (const float*)d_in[12];
    const float* mlp_b1    = (const float*)d_in[13];
    const float* mlp_W2    = (const float*)d_in[14];
    const float* mlp_b2    = (const float*)d_in[15];
    const float* eps       = (const float*)d_in[16];
    const float* bn_gamma  = (const float*)d_in[17];
    const float* bn_beta   = (const float*)d_in[18];
    const float* bn_mean   = (const float*)d_in[19];
    const float* bn_var    = (const float*)d_in[20];
    const float* head_W1   = (const float*)d_in[21];
    const float* head_b1   = (const float*)d_in[22];
    const float* head_W2   = (const float*)d_in[23];
    const float* head_b2   = (const float*)d_in[24];
    float* out = (float*)d_out;

    const int* srcI = ei;
    const int* dstI = ei + N_EDGES;

    // ---- workspace layout ----
    char* w = (char*)d_ws;
    u16*   h      = (u16*)w;                 w += (size_t)N_NODES * HID * 2;   // 51.2 MB
    u16*   zy     = (u16*)w;                 w += (size_t)N_NODES * HID * 2;   // 51.2 MB
    u16*   xbf    = (u16*)w;                 w += (size_t)N_NODES * 64 * 2;    // 12.8 MB
    u16*   Wp1    = (u16*)w;                 w += (size_t)NLAYERS * 65536 * 2;
    u16*   Wp2    = (u16*)w;                 w += (size_t)NLAYERS * 65536 * 2;
    u16*   Wxt    = (u16*)w;                 w += 16384 * 2;
    float* scale2 = (float*)w;               w += NLAYERS * HID * 4;
    float* shift2 = (float*)w;               w += NLAYERS * HID * 4;
    int*   rowptr = (int*)w;                 w += 100032 * 4;
    int*   deg    = (int*)w;                 w += 100032 * 4;
    int*   fill   = (int*)w;                 w += 100032 * 4;
    int*   bsum   = (int*)w;                 w += 512 * 4;
    int*   esrc   = (int*)w;                 w += (size_t)N_EDGES * 4;
    u16*   eap    = (u16*)w;                 w += (size_t)N_EDGES * EDGE_IN * 2; // 8 MB
    float* gsum   = (float*)w;               w += NGRAPH * HID * 4;
    int*   cnt    = (int*)w;                 w += NGRAPH * 4;

    // ---- one-time prep ----
    convw_kernel<<<2048, 256, 0, stream>>>(mlp_W1, Wp1);
    convw_kernel<<<2048, 256, 0, stream>>>(mlp_W2, Wp2);
    convwx_kernel<<<64, 256, 0, stream>>>(xproj_W, Wxt);
    convx_kernel<<<25000, 256, 0, stream>>>(x, xbf);
    bnfold_kernel<<<8, 256, 0, stream>>>(mlp_b2, bn_gamma, bn_beta, bn_mean, bn_var,
                                         scale2, shift2);

    hipMemsetAsync(deg, 0, 2 * 100032 * sizeof(int), stream);  // deg + fill (adjacent)
    deg_count_kernel<<<(N_EDGES + 255) / 256, 256, 0, stream>>>(dstI, deg, N_EDGES);
    scan1_kernel<<<391, 256, 0, stream>>>(deg, rowptr, bsum, N_NODES);
    scan2_kernel<<<1, 64, 0, stream>>>(bsum, 391, rowptr, N_NODES);
    scan3_kernel<<<391, 256, 0, stream>>>(rowptr, bsum, N_NODES);
    scatter_kernel<<<(N_EDGES + 255) / 256, 256, 0, stream>>>(
        srcI, dstI, edge_attr, rowptr, fill, esrc, eap, N_EDGES);

    // ---- x_proj ----
    mfma_gemm<1, true><<<(N_NODES + 127) / 128, 256, 0, stream>>>(
        xbf, Wxt, xproj_b, xp_gamma, xp_beta, xp_mean, xp_var, h, N_NODES);

    const int fgrid = (N_NODES + 63) / 64;
    for (int l = 0; l < NLAYERS; ++l) {
        agg_kernel<<<2048, 256, 0, stream>>>(
            h, eap, rowptr, esrc,
            edge_W + (size_t)l * EDGE_IN * HID, edge_b + (size_t)l * HID,
            eps, l, zy);
        fused_mlp<<<fgrid, 256, 0, stream>>>(
            zy, Wp1 + (size_t)l * 65536, Wp2 + (size_t)l * 65536,
            mlp_b1 + (size_t)l * HID, scale2 + (size_t)l * HID, shift2 + (size_t)l * HID,
            h, N_NODES);
    }

    hipMemsetAsync(gsum, 0, (NGRAPH * HID + NGRAPH) * sizeof(float), stream);
    pool_kernel<<<(N_NODES + 63) / 64, 256, 0, stream>>>(h, batch, gsum, cnt, N_NODES);
    head_kernel<<<NGRAPH, 128, 0, stream>>>(gsum, cnt, head_W1, head_b1, head_W2, head_b2, out);
}